// Round 1
// baseline (107.532 us; speedup 1.0000x reference)
//
#include <hip/hip_runtime.h>
#include <hip/hip_bf16.h>

// Problem constants (match setup_inputs: B=2, N=768, H=W=160)
#define BATCH   2
#define NG      768
#define H_      160
#define W_      160
#define NPIX    (H_ * W_)          // 25600
#define NCHUNK  4
#define CHUNK   (NG / NCHUNK)      // 192
#define EPS2D_  0.3f
#define SZ2_    1.0e-6f            // 0.001^2
#define ALPHA_MAX_ 0.999f
// -0.5 * log2(e): fold into conic so inner loop uses exp2
#define KEXP    (-0.7213475204444817f)

struct __align__(16) GParam {
    float mx, my, A, B2;   // mean, scaled conic terms
    float C, op, cr, cg;   // scaled conic, opacity, color r/g
    float cb, pad0, pad1, pad2;
};

__global__ __launch_bounds__(256)
void gr_precompute(const float* __restrict__ means,
                   const float* __restrict__ scales,
                   const float* __restrict__ rots,
                   const float* __restrict__ colors,
                   const float* __restrict__ opac,
                   GParam* __restrict__ gp, int total) {
    int i = blockIdx.x * blockDim.x + threadIdx.x;
    if (i >= total) return;
    float theta = rots[i];
    float c = cosf(theta), s = sinf(theta);
    float sx = scales[2*i], sy = scales[2*i+1];
    float sx2 = sx*sx, sy2 = sy*sy;
    float a  = c*c*sx2 + s*s*sy2;
    float bb = c*s*(sx2 - sy2);
    float d  = s*s*sx2 + c*c*sy2;
    float mx = means[2*i], my = means[2*i+1];
    float cxx = a + SZ2_*mx*mx + EPS2D_;
    float cxy = bb + SZ2_*mx*my;
    float cyy = d + SZ2_*my*my + EPS2D_;
    float det = cxx*cyy - cxy*cxy;
    float inv = 1.0f / det;
    float ca  =  cyy * inv;
    float cb2 = -cxy * inv;
    float cc  =  cxx * inv;
    GParam g;
    g.mx = mx; g.my = my;
    g.A  = KEXP * ca;
    g.B2 = 2.0f * KEXP * cb2;
    g.C  = KEXP * cc;
    g.op = opac[i];
    g.cr = colors[3*i]; g.cg = colors[3*i+1]; g.cb = colors[3*i+2];
    g.pad0 = 0.f; g.pad1 = 0.f; g.pad2 = 0.f;
    gp[i] = g;
}

// One thread per pixel, one block-y per N-chunk (compositing split associatively).
// Partials stored as float4 (r, g, b, T_chunk).
__global__ __launch_bounds__(256)
void gr_render(const GParam* __restrict__ gp,
               float4* __restrict__ part) {
    int p     = blockIdx.x * 256 + threadIdx.x;   // [0, NPIX)
    int chunk = blockIdx.y;
    int b     = blockIdx.z;
    float px = (float)(p % W_) + 0.5f;
    float py = (float)(p / W_) + 0.5f;
    const GParam* __restrict__ g = gp + b * NG + chunk * CHUNK;

    float r = 0.f, gg = 0.f, bl = 0.f, T = 1.f;

    for (int t0 = 0; t0 < CHUNK; t0 += 16) {
        #pragma unroll
        for (int k = 0; k < 16; ++k) {
            GParam gv = g[t0 + k];                 // wave-uniform address -> s_load expected
            float dx = px - gv.mx;
            float dy = py - gv.my;
            float u  = gv.A * dx;
            u        = fmaf(gv.B2, dy, u);
            float t  = gv.C * dy;
            t        = t * dy;
            float q  = fmaf(dx, u, t);             // = -0.5*log2e * mahalanobis^2  (<= 0)
            float al = gv.op * __builtin_exp2f(q);
            al       = fminf(al, ALPHA_MAX_);
            float w  = T * al;
            r  = fmaf(w, gv.cr, r);
            gg = fmaf(w, gv.cg, gg);
            bl = fmaf(w, gv.cb, bl);
            T -= w;
        }
        // chunk-local early exit: remaining contribution bounded by T < 1e-4
        if (__all(T < 1.0e-4f)) break;
    }
    part[(chunk * BATCH + b) * NPIX + p] = make_float4(r, gg, bl, T);
}

__global__ __launch_bounds__(256)
void gr_combine(const float4* __restrict__ part, float* __restrict__ out) {
    int idx = blockIdx.x * 256 + threadIdx.x;     // [0, BATCH*NPIX)
    if (idx >= BATCH * NPIX) return;
    int b = idx / NPIX;
    int p = idx - b * NPIX;
    float4 o0 = part[(0 * BATCH + b) * NPIX + p];
    float4 o1 = part[(1 * BATCH + b) * NPIX + p];
    float4 o2 = part[(2 * BATCH + b) * NPIX + p];
    float4 o3 = part[(3 * BATCH + b) * NPIX + p];
    float r  = o0.x + o0.w * (o1.x + o1.w * (o2.x + o2.w * o3.x));
    float gg = o0.y + o0.w * (o1.y + o1.w * (o2.y + o2.w * o3.y));
    float bb = o0.z + o0.w * (o1.z + o1.w * (o2.z + o2.w * o3.z));
    r  = fminf(fmaxf(r , 0.f), 1.f);
    gg = fminf(fmaxf(gg, 0.f), 1.f);
    bb = fminf(fmaxf(bb, 0.f), 1.f);
    out[(b * 3 + 0) * NPIX + p] = r;
    out[(b * 3 + 1) * NPIX + p] = gg;
    out[(b * 3 + 2) * NPIX + p] = bb;
}

extern "C" void kernel_launch(void* const* d_in, const int* in_sizes, int n_in,
                              void* d_out, int out_size, void* d_ws, size_t ws_size,
                              hipStream_t stream) {
    const float* means  = (const float*)d_in[0];
    const float* scales = (const float*)d_in[1];
    const float* rots   = (const float*)d_in[2];
    const float* colors = (const float*)d_in[3];
    const float* opac   = (const float*)d_in[4];
    float* out = (float*)d_out;

    GParam* gp = (GParam*)d_ws;
    size_t gp_bytes = (size_t)BATCH * NG * sizeof(GParam);
    gp_bytes = (gp_bytes + 255) & ~(size_t)255;
    float4* part = (float4*)((char*)d_ws + gp_bytes);

    int total = BATCH * NG;
    gr_precompute<<<(total + 255) / 256, 256, 0, stream>>>(
        means, scales, rots, colors, opac, gp, total);

    dim3 rgrid(NPIX / 256, NCHUNK, BATCH);   // (100, 4, 2)
    gr_render<<<rgrid, 256, 0, stream>>>(gp, part);

    gr_combine<<<(BATCH * NPIX + 255) / 256, 256, 0, stream>>>(part, out);
}